// Round 3
// baseline (315122.729 us; speedup 1.0000x reference)
//
#include <hip/hip_runtime.h>
#include <math.h>

// Problem constants
#define NN 1024
#define MM 64
#define CC 512
#define LL 64
#define TT 8192
#define EPSF 1e-16f

// Flat output offsets (return order: seq_out, ww_h, rw_h, a_h, r_h)
#define OFF_SEQ 0
#define OFF_WW  (TT*LL)                  // 524288
#define OFF_RW  (OFF_WW + TT*NN)         // 8912896
#define OFF_A   (OFF_RW + TT*NN)         // 17301504
#define OFF_R   (OFF_A + TT*MM)          // 17825792

__device__ __forceinline__ float sigmoid_f(float x) { return 1.0f / (1.0f + __expf(-x)); }
__device__ __forceinline__ float softplus_f(float x) { return (x > 15.0f) ? x : __logf(1.0f + __expf(x)); }
__device__ __forceinline__ float tanh_f(float x) { float e = __expf(2.0f * x); return 1.0f - 2.0f / (e + 1.0f); }
__device__ __forceinline__ float pow_f(float b, float g) { return __expf(g * __logf(b)); }  // b >= 0
__device__ __forceinline__ int bitrev4(int l) {
    return ((l & 1) << 3) | ((l & 2) << 1) | ((l & 4) >> 1) | ((l & 8) >> 3);
}

// Kernel 1: pre[t][j] = sum_i seq[t][i] * Wc[i][j] + bc[j]   (s-part of controller input)
__global__ void pre_kernel(const float* __restrict__ seq, const float* __restrict__ Wc,
                           const float* __restrict__ bc, float* __restrict__ pre) {
    int gid = blockIdx.x * blockDim.x + threadIdx.x;  // t*CC + j
    int t = gid >> 9;
    int j = gid & 511;
    if (t >= TT) return;
    const float* s = seq + t * LL;
    float acc = bc[j];
    #pragma unroll 8
    for (int i = 0; i < LL; ++i) acc += s[i] * Wc[i * CC + j];
    pre[gid] = acc;
}

// Kernel 2: persistent single workgroup, 1024 threads, thread t owns memory row t in VGPRs.
// amdgpu_waves_per_eu(4,4): exactly 4 waves/EU (the one 16-wave block) => register allocator
// budget = 512/4 = 128 VGPRs/wave, so Mrow[64] stays in registers. Round-2's
// __launch_bounds__(1024,4) left VGPR_Count at 64 and Mrow spilled to scratch
// (FETCH_SIZE 9.8 GB of L2-miss traffic); this attribute is the direct backend control.
__global__
__attribute__((amdgpu_flat_work_group_size(1024, 1024), amdgpu_waves_per_eu(4, 4)))
void ntm_kernel(
    const float* __restrict__ pre,  // [TT][CC]
    const float* __restrict__ Wc,   // [128][512]
    const float* __restrict__ Wr,   // [512][70]
    const float* __restrict__ br,   // [70]
    const float* __restrict__ Ww,   // [512][198]
    const float* __restrict__ bw,   // [198]
    const float* __restrict__ Wo,   // [64][64]
    const float* __restrict__ bo,   // [64]
    float* __restrict__ out)
{
    __shared__ __align__(16) float sh_h[CC];          // controller hidden
    __shared__ __align__(16) float sh_part[1088];     // partial sums (h stage: 1024, ow stage: 4x272)
    __shared__ __align__(16) float sh_ow[272];        // [0..197]=ow, [198..267]=orr
    __shared__ __align__(16) float sh_kw[MM];
    __shared__ __align__(16) float sh_kr[MM];
    __shared__ __align__(16) float sh_e[MM];
    __shared__ __align__(16) float sh_a[MM];
    __shared__ __align__(16) float sh_scal[16];       // 0:bW 1:gW 2..4:shW 5:gamW 6:|kW| ; 8:bR 9:gR 10..12:shR 13:gamR 14:|kR|
    __shared__ __align__(16) float sh_evbuf[NN];
    __shared__ __align__(16) float sh_wpbuf[NN];
    __shared__ __align__(16) float red[4][16];        // 0:evW 1:wshW 2:evR 3:wshR per-wave partials
    __shared__ __align__(16) float wmat[16][MM];      // per-wave partial r_n columns
    __shared__ __align__(16) float sh_r[MM];
    __shared__ __align__(16) float sh_Wo[MM * LL];
    __shared__ __align__(16) float sh_bo[LL];
    __shared__ __align__(16) float sh_bw[200];
    __shared__ __align__(16) float sh_br[72];
    __shared__ __align__(16) float sh_pren[CC];       // prefetched pre[t+1]

    const int tid  = threadIdx.x;
    const int lane = tid & 63;
    const int wv   = tid >> 6;

    // ---- preload constants into LDS, init state ----
    for (int i = tid; i < MM * LL; i += NN) sh_Wo[i] = Wo[i];
    if (tid < LL)  sh_bo[tid] = bo[tid];
    if (tid < 198) sh_bw[tid] = bw[tid];
    if (tid < 70)  sh_br[tid] = br[tid];
    if (tid < MM)  sh_r[tid] = 1e-6f;            // read_bias
    if (tid < CC)  sh_pren[tid] = pre[tid];      // prefetch pre[0]

    float Mrow[MM];
    #pragma unroll
    for (int j = 0; j < MM; ++j) Mrow[j] = 1e-6f;   // memory_bias
    float rown = sqrtf(64.0f * 1e-12f);

    float wwprev = (tid == NN / 2) ? 1.0f : 0.0f;   // weight_bias one-hot
    float rwprev = wwprev;
    __syncthreads();

    for (int t = 0; t < TT; ++t) {
        // ================= h = tanh(pre + r @ Wc[64:128]) =================
        {
            int j = tid & 511, half = tid >> 9;
            const float* wc2 = Wc + (64 + half * 32) * CC + j;
            const float4* r4p = (const float4*)(sh_r + half * 32);
            float a0 = 0.0f, a1 = 0.0f;
            #pragma unroll
            for (int i4 = 0; i4 < 8; ++i4) {
                float4 r4 = r4p[i4];
                const float* w = wc2 + (i4 * 4) * CC;
                a0 += r4.x * w[0] + r4.y * w[CC];
                a1 += r4.z * w[2 * CC] + r4.w * w[3 * CC];
            }
            sh_part[tid] = a0 + a1;
        }
        __syncthreads();  // s1
        if (tid < CC) {
            float v = sh_pren[tid] + sh_part[tid] + sh_part[tid + CC];
            sh_h[tid] = tanh_f(v);
        }
        __syncthreads();  // s2

        // ================= ow = h@Ww+bw ; orr = h@Wr+br =================
        // 4 row-quarters (128 rows each) x 268 columns; all 1024 threads active.
        {
            int c = tid & 255;          // column 0..255
            int q = tid >> 8;           // row quarter 0..3
            const float* Wp; int ncol, col;
            if (c < 198) { Wp = Ww; ncol = 198; col = c; }
            else         { Wp = Wr; ncol = 70;  col = c - 198; }
            const float* wptr = Wp + (q * 128) * ncol + col;
            const float4* h4 = (const float4*)(sh_h + q * 128);
            float a0 = 0.0f, a1 = 0.0f;
            #pragma unroll 8
            for (int i4 = 0; i4 < 32; ++i4) {
                float4 h = h4[i4];
                const float* w = wptr + (i4 * 4) * ncol;
                a0 += h.x * w[0] + h.y * w[ncol];
                a1 += h.z * w[2 * ncol] + h.w * w[3 * ncol];
            }
            sh_part[q * 272 + c] = a0 + a1;
        }
        if (tid < 48) {                 // tail columns 256..267 (Wr cols 58..69)
            int c = 256 + (tid >> 2);
            int q = tid & 3;
            int col = c - 198;
            const float* wptr = Wr + (q * 128) * 70 + col;
            const float4* h4 = (const float4*)(sh_h + q * 128);
            float a0 = 0.0f, a1 = 0.0f;
            #pragma unroll 8
            for (int i4 = 0; i4 < 32; ++i4) {
                float4 h = h4[i4];
                const float* w = wptr + (i4 * 4) * 70;
                a0 += h.x * w[0] + h.y * w[70];
                a1 += h.z * w[140] + h.w * w[210];
            }
            sh_part[q * 272 + c] = a0 + a1;
        }
        __syncthreads();  // s3
        if (tid < 268) {
            float b = (tid < 198) ? sh_bw[tid] : sh_br[tid - 198];
            sh_ow[tid] = ((sh_part[tid] + sh_part[272 + tid])
                        + (sh_part[544 + tid] + sh_part[816 + tid])) + b;
        }
        __syncthreads();  // s4

        // ================= head parameter transforms (+ pre[t+1] prefetch) =================
        if (wv == 0) {                       // write key + its norm
            float v = tanh_f(sh_ow[lane]);
            sh_kw[lane] = v;
            float s2 = v * v;
            #pragma unroll
            for (int m = 1; m < 64; m <<= 1) s2 += __shfl_xor(s2, m, 64);
            if (lane == 0) sh_scal[6] = sqrtf(s2);
        } else if (wv == 1) {                // read key + its norm
            float v = tanh_f(sh_ow[198 + lane]);
            sh_kr[lane] = v;
            float s2 = v * v;
            #pragma unroll
            for (int m = 1; m < 64; m <<= 1) s2 += __shfl_xor(s2, m, 64);
            if (lane == 0) sh_scal[14] = sqrtf(s2);
        } else if (wv == 2) {                // erase
            sh_e[lane] = sigmoid_f(sh_ow[70 + lane]);
        } else if (wv == 3) {                // add (also an output)
            float v = tanh_f(sh_ow[134 + lane]);
            sh_a[lane] = v;
            out[OFF_A + t * MM + lane] = v;
        } else if (wv == 4) {                // write-head scalars
            if (lane == 0) {
                sh_scal[0] = softplus_f(sh_ow[64]);
                sh_scal[1] = sigmoid_f(sh_ow[65]);
                float x0 = sh_ow[66], x1 = sh_ow[67], x2 = sh_ow[68];
                float mx = fmaxf(x0, fmaxf(x1, x2));
                float e0 = __expf(x0 - mx), e1 = __expf(x1 - mx), e2 = __expf(x2 - mx);
                float ss = e0 + e1 + e2;
                sh_scal[2] = e0 / ss; sh_scal[3] = e1 / ss; sh_scal[4] = e2 / ss;
                sh_scal[5] = 1.0f + softplus_f(sh_ow[69]);
            }
        } else if (wv == 5) {                // read-head scalars
            if (lane == 0) {
                sh_scal[8] = softplus_f(sh_ow[198 + 64]);
                sh_scal[9] = sigmoid_f(sh_ow[198 + 65]);
                float x0 = sh_ow[198 + 66], x1 = sh_ow[198 + 67], x2 = sh_ow[198 + 68];
                float mx = fmaxf(x0, fmaxf(x1, x2));
                float e0 = __expf(x0 - mx), e1 = __expf(x1 - mx), e2 = __expf(x2 - mx);
                float ss = e0 + e1 + e2;
                sh_scal[10] = e0 / ss; sh_scal[11] = e1 / ss; sh_scal[12] = e2 / ss;
                sh_scal[13] = 1.0f + softplus_f(sh_ow[198 + 69]);
            }
        } else if (wv >= 6 && wv < 14) {     // prefetch pre[t+1] into LDS (512 idle threads)
            if (t + 1 < TT) sh_pren[tid - 384] = pre[(t + 1) * CC + (tid - 384)];
        }
        __syncthreads();  // s5

        // ================= write addressing =================
        float betaW = sh_scal[0], gW = sh_scal[1];
        float s0W = sh_scal[2], s1W = sh_scal[3], s2W = sh_scal[4];
        float gamW = sh_scal[5], knW = sh_scal[6];
        {
            const float4* k4 = (const float4*)sh_kw;
            float d0 = 0.0f, d1 = 0.0f, d2 = 0.0f, d3 = 0.0f;
            #pragma unroll
            for (int j4 = 0; j4 < 16; ++j4) {
                float4 k = k4[j4];
                d0 += Mrow[4*j4]   * k.x;
                d1 += Mrow[4*j4+1] * k.y;
                d2 += Mrow[4*j4+2] * k.z;
                d3 += Mrow[4*j4+3] * k.w;
            }
            float dot = (d0 + d1) + (d2 + d3);
            float sim = dot / (rown * knW + EPSF);
            float ev = __expf(betaW * sim);
            sh_evbuf[tid] = ev;
            sh_wpbuf[tid] = wwprev;
            float s = ev;
            #pragma unroll
            for (int m = 1; m < 64; m <<= 1) s += __shfl_xor(s, m, 64);
            if (lane == 0) red[0][wv] = s;
        }
        __syncthreads();  // s6
        float wshW;
        {
            const float4* rp = (const float4*)red[0];
            float Sev = 0.0f;
            #pragma unroll
            for (int w4 = 0; w4 < 4; ++w4) { float4 p = rp[w4]; Sev += p.x + p.y + p.z + p.w; }
            int tm1 = (tid + NN - 1) & (NN - 1), tp1 = (tid + 1) & (NN - 1);
            float cEV = s0W * sh_evbuf[tm1] + s1W * sh_evbuf[tid] + s2W * sh_evbuf[tp1];
            float cWP = s0W * sh_wpbuf[tm1] + s1W * sh_wpbuf[tid] + s2W * sh_wpbuf[tp1];
            float ws = (gW / Sev) * cEV + (1.0f - gW) * cWP;   // conv is linear in wg
            wshW = pow_f(ws, gamW);
            float s = wshW;
            #pragma unroll
            for (int m = 1; m < 64; m <<= 1) s += __shfl_xor(s, m, 64);
            if (lane == 0) red[1][wv] = s;
        }
        __syncthreads();  // s7
        {
            const float4* rp = (const float4*)red[1];
            float Swsh = 0.0f;
            #pragma unroll
            for (int w4 = 0; w4 < 4; ++w4) { float4 p = rp[w4]; Swsh += p.x + p.y + p.z + p.w; }
            float wwn = wshW / (Swsh + EPSF);
            out[OFF_WW + t * NN + tid] = wwn;
            wwprev = wwn;
            // memory update + norm recompute (element-independent; 4 nsq accumulators)
            const float4* e4p = (const float4*)sh_e;
            const float4* a4p = (const float4*)sh_a;
            float n0 = 0.0f, n1 = 0.0f, n2 = 0.0f, n3 = 0.0f;
            #pragma unroll
            for (int j4 = 0; j4 < 16; ++j4) {
                float4 e = e4p[j4], a = a4p[j4];
                float m0 = Mrow[4*j4]   * (1.0f - wwn * e.x) + wwn * a.x;
                float m1 = Mrow[4*j4+1] * (1.0f - wwn * e.y) + wwn * a.y;
                float m2 = Mrow[4*j4+2] * (1.0f - wwn * e.z) + wwn * a.z;
                float m3 = Mrow[4*j4+3] * (1.0f - wwn * e.w) + wwn * a.w;
                Mrow[4*j4] = m0; Mrow[4*j4+1] = m1; Mrow[4*j4+2] = m2; Mrow[4*j4+3] = m3;
                n0 += m0 * m0; n1 += m1 * m1; n2 += m2 * m2; n3 += m3 * m3;
            }
            rown = sqrtf((n0 + n1) + (n2 + n3));
        }

        // ================= read addressing (on updated Mt) =================
        float betaR = sh_scal[8], gR = sh_scal[9];
        float s0R = sh_scal[10], s1R = sh_scal[11], s2R = sh_scal[12];
        float gamR = sh_scal[13], knR = sh_scal[14];
        {
            const float4* k4 = (const float4*)sh_kr;
            float d0 = 0.0f, d1 = 0.0f, d2 = 0.0f, d3 = 0.0f;
            #pragma unroll
            for (int j4 = 0; j4 < 16; ++j4) {
                float4 k = k4[j4];
                d0 += Mrow[4*j4]   * k.x;
                d1 += Mrow[4*j4+1] * k.y;
                d2 += Mrow[4*j4+2] * k.z;
                d3 += Mrow[4*j4+3] * k.w;
            }
            float dot = (d0 + d1) + (d2 + d3);
            float sim = dot / (rown * knR + EPSF);
            float ev = __expf(betaR * sim);
            sh_evbuf[tid] = ev;   // safe: all write-phase conv reads completed before s7
            sh_wpbuf[tid] = rwprev;
            float s = ev;
            #pragma unroll
            for (int m = 1; m < 64; m <<= 1) s += __shfl_xor(s, m, 64);
            if (lane == 0) red[2][wv] = s;
        }
        __syncthreads();  // s8
        float wshR;
        {
            const float4* rp = (const float4*)red[2];
            float Sev = 0.0f;
            #pragma unroll
            for (int w4 = 0; w4 < 4; ++w4) { float4 p = rp[w4]; Sev += p.x + p.y + p.z + p.w; }
            int tm1 = (tid + NN - 1) & (NN - 1), tp1 = (tid + 1) & (NN - 1);
            float cEV = s0R * sh_evbuf[tm1] + s1R * sh_evbuf[tid] + s2R * sh_evbuf[tp1];
            float cWP = s0R * sh_wpbuf[tm1] + s1R * sh_wpbuf[tid] + s2R * sh_wpbuf[tp1];
            float ws = (gR / Sev) * cEV + (1.0f - gR) * cWP;
            wshR = pow_f(ws, gamR);
            float s = wshR;
            #pragma unroll
            for (int m = 1; m < 64; m <<= 1) s += __shfl_xor(s, m, 64);
            if (lane == 0) red[3][wv] = s;

            // r_n partial: per-wave column sums of wshR * Mrow via recursive-halving
            // transpose-reduce, four 16-column chunks (payload v[16] keeps VGPRs < 128).
            #pragma unroll
            for (int chunk = 0; chunk < 4; ++chunk) {
                const int cb = chunk * 16;
                float v[16];
                #pragma unroll
                for (int i = 0; i < 16; ++i) v[i] = wshR * Mrow[cb + i];
                #pragma unroll
                for (int st = 0; st < 4; ++st) {
                    const int m = 1 << st;
                    const int hs = 8 >> st;
                    bool hi = (lane & m) != 0;
                    #pragma unroll
                    for (int i = 0; i < 8; ++i) {
                        if (i < hs) {
                            float send = hi ? v[i] : v[i + hs];
                            float recv = __shfl_xor(send, m, 64);
                            float keep = hi ? v[i + hs] : v[i];
                            v[i] = keep + recv;
                        }
                    }
                }
                float v0 = v[0];
                v0 += __shfl_xor(v0, 16, 64);
                v0 += __shfl_xor(v0, 32, 64);
                if (lane < 16) wmat[wv][cb + bitrev4(lane)] = v0;
            }
        }
        __syncthreads();  // s9
        {
            const float4* rp = (const float4*)red[3];
            float Swsh = 0.0f;
            #pragma unroll
            for (int w4 = 0; w4 < 4; ++w4) { float4 p = rp[w4]; Swsh += p.x + p.y + p.z + p.w; }
            float inv = 1.0f / (Swsh + EPSF);
            float rwn = wshR * inv;
            out[OFF_RW + t * NN + tid] = rwn;
            rwprev = rwn;
            if (tid < MM) {
                float rv = 0.0f;
                #pragma unroll
                for (int w = 0; w < 16; ++w) rv += wmat[w][tid];
                rv *= inv;
                sh_r[tid] = rv;
                out[OFF_R + t * MM + tid] = rv;
            }
        }
        __syncthreads();  // s10
        if (tid < LL) {
            const float4* r4p = (const float4*)sh_r;
            float a0 = 0.0f, a1 = 0.0f;
            #pragma unroll
            for (int i4 = 0; i4 < 16; ++i4) {
                float4 r = r4p[i4];
                a0 += r.x * sh_Wo[(4*i4) * LL + tid]   + r.y * sh_Wo[(4*i4+1) * LL + tid];
                a1 += r.z * sh_Wo[(4*i4+2) * LL + tid] + r.w * sh_Wo[(4*i4+3) * LL + tid];
            }
            float acc = sh_bo[tid] + a0 + a1;
            out[OFF_SEQ + t * LL + tid] = fminf(fmaxf(acc, 0.0f), 1.0f);
        }
        // no sync needed: next h-stage only reads sh_r (stable until next s9)
    }
}

extern "C" void kernel_launch(void* const* d_in, const int* in_sizes, int n_in,
                              void* d_out, int out_size, void* d_ws, size_t ws_size,
                              hipStream_t stream) {
    const float* seq = (const float*)d_in[0];
    const float* Wc  = (const float*)d_in[1];
    const float* bc  = (const float*)d_in[2];
    const float* Wr  = (const float*)d_in[3];
    const float* br  = (const float*)d_in[4];
    const float* Ww  = (const float*)d_in[5];
    const float* bw  = (const float*)d_in[6];
    const float* Wo  = (const float*)d_in[7];
    const float* bo  = (const float*)d_in[8];
    float* out = (float*)d_out;
    float* pre = (float*)d_ws;   // needs TT*CC*4 = 16 MB of workspace

    pre_kernel<<<(TT * CC) / 256, 256, 0, stream>>>(seq, Wc, bc, pre);
    ntm_kernel<<<1, 1024, 0, stream>>>(pre, Wc, Wr, br, Ww, bw, Wo, bo, out);
}

// Round 5
// 243265.552 us; speedup vs baseline: 1.2954x; 1.2954x over previous
//
#include <hip/hip_runtime.h>
#include <math.h>

// Problem constants
#define NN 1024
#define MM 64
#define CC 512
#define LL 64
#define TT 8192
#define EPSF 1e-16f

// Flat output offsets (return order: seq_out, ww_h, rw_h, a_h, r_h)
#define OFF_SEQ 0
#define OFF_WW  (TT*LL)                  // 524288
#define OFF_RW  (OFF_WW + TT*NN)         // 8912896
#define OFF_A   (OFF_RW + TT*NN)         // 17301504
#define OFF_R   (OFF_A + TT*MM)          // 17825792

__device__ __forceinline__ float sigmoid_f(float x) { return 1.0f / (1.0f + __expf(-x)); }
__device__ __forceinline__ float softplus_f(float x) { return (x > 15.0f) ? x : __logf(1.0f + __expf(x)); }
__device__ __forceinline__ float tanh_f(float x) { float e = __expf(2.0f * x); return 1.0f - 2.0f / (e + 1.0f); }
__device__ __forceinline__ float pow_f(float b, float g) { return __expf(g * __logf(b)); }  // b >= 0
__device__ __forceinline__ int bitrev4(int l) {
    return ((l & 1) << 3) | ((l & 2) << 1) | ((l & 4) >> 1) | ((l & 8) >> 3);
}

// Kernel 1: pre[t][j] = sum_i seq[t][i] * Wc[i][j] + bc[j]   (s-part of controller input)
__global__ void pre_kernel(const float* __restrict__ seq, const float* __restrict__ Wc,
                           const float* __restrict__ bc, float* __restrict__ pre) {
    int gid = blockIdx.x * blockDim.x + threadIdx.x;  // t*CC + j
    int t = gid >> 9;
    int j = gid & 511;
    if (t >= TT) return;
    const float* s = seq + t * LL;
    float acc = bc[j];
    #pragma unroll 8
    for (int i = 0; i < LL; ++i) acc += s[i] * Wc[i * CC + j];
    pre[gid] = acc;
}

// Kernel 2: persistent single workgroup, 1024 threads, thread t owns memory row t.
// fp32 everywhere in the recurrent loop (round-4 f16 diverged: absmax 0.617 — the
// addressing feedback amplifies ~1e-3 perturbations ~600x).
// M column-split: cols 0..31 in 32 VGPRs; cols 32..63 in d_ws as per-thread-private
// float4-interleaved storage (ws_m[k*NN+tid], coalesced 1KB/wave-instr), loaded once
// per step and HELD in registers through update -> read-dot -> transpose, stored once.
// Peak live ~95 regs < 128 (64 arch + AGPR) => no scratch spill (rounds 1-3 needed
// ~160 and spilled: ~70% of step time was scratch latency).
__global__
__attribute__((amdgpu_flat_work_group_size(1024, 1024), amdgpu_waves_per_eu(4)))
void ntm_kernel(
    const float* __restrict__ pre,  // [TT][CC]
    const float* __restrict__ Wc,   // [128][512]
    const float* __restrict__ Wr,   // [512][70]
    const float* __restrict__ br,   // [70]
    const float* __restrict__ Ww,   // [512][198]
    const float* __restrict__ bw,   // [198]
    const float* __restrict__ Wo,   // [64][64]
    const float* __restrict__ bo,   // [64]
    float* __restrict__ out,
    float4* __restrict__ ws_m)      // [8][1024] private M cols 32..63
{
    __shared__ __align__(16) float sh_h[CC];          // controller hidden
    __shared__ __align__(16) float sh_part[1088];     // partial sums
    __shared__ __align__(16) float sh_ow[272];        // [0..197]=ow, [198..267]=orr
    __shared__ __align__(16) float sh_kw[MM];
    __shared__ __align__(16) float sh_kr[MM];
    __shared__ __align__(16) float sh_e[MM];
    __shared__ __align__(16) float sh_a[MM];
    __shared__ __align__(16) float sh_scal[16];
    __shared__ __align__(16) float sh_evbuf[NN];
    __shared__ __align__(16) float sh_wpbuf[NN];
    __shared__ __align__(16) float red[4][16];
    __shared__ __align__(16) float wmat[16][MM];
    __shared__ __align__(16) float sh_r[MM];
    __shared__ __align__(16) float sh_Wo[MM * LL];
    __shared__ __align__(16) float sh_bo[LL];
    __shared__ __align__(16) float sh_bw[200];
    __shared__ __align__(16) float sh_br[72];
    __shared__ __align__(16) float sh_pren[CC];       // prefetched pre[t+1]

    const int tid  = threadIdx.x;
    const int lane = tid & 63;
    const int wv   = tid >> 6;

    // ---- preload constants into LDS, init state ----
    for (int i = tid; i < MM * LL; i += NN) sh_Wo[i] = Wo[i];
    if (tid < LL)  sh_bo[tid] = bo[tid];
    if (tid < 198) sh_bw[tid] = bw[tid];
    if (tid < 70)  sh_br[tid] = br[tid];
    if (tid < MM)  sh_r[tid] = 1e-6f;            // read_bias
    if (tid < CC)  sh_pren[tid] = pre[tid];      // prefetch pre[0]

    float Mlo[32];                               // cols 0..31
    #pragma unroll
    for (int j = 0; j < 32; ++j) Mlo[j] = 1e-6f;
    float4 mh[8];                                // cols 32..63 (live most of each step)
    #pragma unroll
    for (int k = 0; k < 8; ++k) {
        mh[k] = make_float4(1e-6f, 1e-6f, 1e-6f, 1e-6f);
        ws_m[k * NN + tid] = mh[k];              // init private store (d_ws is poisoned)
    }
    float rown = sqrtf(64.0f * 1e-12f);

    float wwprev = (tid == NN / 2) ? 1.0f : 0.0f;   // weight_bias one-hot
    float rwprev = wwprev;
    __syncthreads();

    for (int t = 0; t < TT; ++t) {
        // ================= h = tanh(pre + r @ Wc[64:128]) =================
        {
            int j = tid & 511, half = tid >> 9;
            const float* wc2 = Wc + (64 + half * 32) * CC + j;
            const float4* r4p = (const float4*)(sh_r + half * 32);
            float a0 = 0.0f, a1 = 0.0f;
            #pragma unroll
            for (int i4 = 0; i4 < 8; ++i4) {
                float4 r4 = r4p[i4];
                const float* w = wc2 + (i4 * 4) * CC;
                a0 += r4.x * w[0] + r4.y * w[CC];
                a1 += r4.z * w[2 * CC] + r4.w * w[3 * CC];
            }
            sh_part[tid] = a0 + a1;
        }
        __syncthreads();  // s1
        if (tid < CC) {
            float v = sh_pren[tid] + sh_part[tid] + sh_part[tid + CC];
            sh_h[tid] = tanh_f(v);
        }
        __syncthreads();  // s2

        // ================= ow = h@Ww+bw ; orr = h@Wr+br =================
        if (tid < 536) {
            int q = (tid < 268) ? 0 : 1;
            int c = tid - q * 268;
            const float* Wp; int ncol, col;
            if (c < 198) { Wp = Ww; ncol = 198; col = c; }
            else         { Wp = Wr; ncol = 70;  col = c - 198; }
            const float* wptr = Wp + (q * 256) * ncol + col;
            const float4* h4 = (const float4*)(sh_h + q * 256);
            float a0 = 0.0f, a1 = 0.0f;
            #pragma unroll 8
            for (int i4 = 0; i4 < 64; ++i4) {
                float4 h = h4[i4];
                const float* w = wptr + (i4 * 4) * ncol;
                a0 += h.x * w[0] + h.y * w[ncol];
                a1 += h.z * w[2 * ncol] + h.w * w[3 * ncol];
            }
            sh_part[tid] = a0 + a1;
        }
        __syncthreads();  // s3
        if (tid < 268) {
            float b = (tid < 198) ? sh_bw[tid] : sh_br[tid - 198];
            sh_ow[tid] = sh_part[tid] + sh_part[tid + 268] + b;
        }
        __syncthreads();  // s4

        // ================= head parameter transforms (+ pre[t+1] prefetch) =================
        if (wv == 0) {                       // write key + its norm
            float v = tanh_f(sh_ow[lane]);
            sh_kw[lane] = v;
            float s2 = v * v;
            #pragma unroll
            for (int m = 1; m < 64; m <<= 1) s2 += __shfl_xor(s2, m, 64);
            if (lane == 0) sh_scal[6] = sqrtf(s2);
        } else if (wv == 1) {                // read key + its norm
            float v = tanh_f(sh_ow[198 + lane]);
            sh_kr[lane] = v;
            float s2 = v * v;
            #pragma unroll
            for (int m = 1; m < 64; m <<= 1) s2 += __shfl_xor(s2, m, 64);
            if (lane == 0) sh_scal[14] = sqrtf(s2);
        } else if (wv == 2) {                // erase
            sh_e[lane] = sigmoid_f(sh_ow[70 + lane]);
        } else if (wv == 3) {                // add (also an output)
            float v = tanh_f(sh_ow[134 + lane]);
            sh_a[lane] = v;
            out[OFF_A + t * MM + lane] = v;
        } else if (wv == 4) {                // write-head scalars
            if (lane == 0) {
                sh_scal[0] = softplus_f(sh_ow[64]);
                sh_scal[1] = sigmoid_f(sh_ow[65]);
                float x0 = sh_ow[66], x1 = sh_ow[67], x2 = sh_ow[68];
                float mx = fmaxf(x0, fmaxf(x1, x2));
                float e0 = __expf(x0 - mx), e1 = __expf(x1 - mx), e2 = __expf(x2 - mx);
                float ss = e0 + e1 + e2;
                sh_scal[2] = e0 / ss; sh_scal[3] = e1 / ss; sh_scal[4] = e2 / ss;
                sh_scal[5] = 1.0f + softplus_f(sh_ow[69]);
            }
        } else if (wv == 5) {                // read-head scalars
            if (lane == 0) {
                sh_scal[8] = softplus_f(sh_ow[198 + 64]);
                sh_scal[9] = sigmoid_f(sh_ow[198 + 65]);
                float x0 = sh_ow[198 + 66], x1 = sh_ow[198 + 67], x2 = sh_ow[198 + 68];
                float mx = fmaxf(x0, fmaxf(x1, x2));
                float e0 = __expf(x0 - mx), e1 = __expf(x1 - mx), e2 = __expf(x2 - mx);
                float ss = e0 + e1 + e2;
                sh_scal[10] = e0 / ss; sh_scal[11] = e1 / ss; sh_scal[12] = e2 / ss;
                sh_scal[13] = 1.0f + softplus_f(sh_ow[198 + 69]);
            }
        } else if (wv >= 6 && wv < 14) {     // prefetch pre[t+1] into LDS (512 idle threads)
            if (t + 1 < TT) sh_pren[tid - 384] = pre[(t + 1) * CC + (tid - 384)];
        }
        __syncthreads();  // s5

        // ================= write addressing =================
        float betaW = sh_scal[0], gW = sh_scal[1];
        float s0W = sh_scal[2], s1W = sh_scal[3], s2W = sh_scal[4];
        float gamW = sh_scal[5], knW = sh_scal[6];
        {
            // reload M cols 32..63 (written by this same thread last step)
            #pragma unroll
            for (int k = 0; k < 8; ++k) mh[k] = ws_m[k * NN + tid];
            const float4* k4 = (const float4*)sh_kw;
            float d0 = 0.0f, d1 = 0.0f, d2 = 0.0f, d3 = 0.0f;
            #pragma unroll
            for (int j4 = 0; j4 < 8; ++j4) {
                float4 k = k4[j4];
                d0 += Mlo[4*j4]   * k.x;
                d1 += Mlo[4*j4+1] * k.y;
                d2 += Mlo[4*j4+2] * k.z;
                d3 += Mlo[4*j4+3] * k.w;
            }
            #pragma unroll
            for (int k8 = 0; k8 < 8; ++k8) {
                float4 k = k4[8 + k8];
                d0 += mh[k8].x * k.x;
                d1 += mh[k8].y * k.y;
                d2 += mh[k8].z * k.z;
                d3 += mh[k8].w * k.w;
            }
            float dot = (d0 + d1) + (d2 + d3);
            float sim = dot / (rown * knW + EPSF);
            float ev = __expf(betaW * sim);
            sh_evbuf[tid] = ev;
            sh_wpbuf[tid] = wwprev;
            float s = ev;
            #pragma unroll
            for (int m = 1; m < 64; m <<= 1) s += __shfl_xor(s, m, 64);
            if (lane == 0) red[0][wv] = s;
        }
        __syncthreads();  // s6
        float wshW;
        {
            const float4* rp = (const float4*)red[0];
            float Sev = 0.0f;
            #pragma unroll
            for (int w4 = 0; w4 < 4; ++w4) { float4 p = rp[w4]; Sev += p.x + p.y + p.z + p.w; }
            int tm1 = (tid + NN - 1) & (NN - 1), tp1 = (tid + 1) & (NN - 1);
            float cEV = s0W * sh_evbuf[tm1] + s1W * sh_evbuf[tid] + s2W * sh_evbuf[tp1];
            float cWP = s0W * sh_wpbuf[tm1] + s1W * sh_wpbuf[tid] + s2W * sh_wpbuf[tp1];
            float ws = (gW / Sev) * cEV + (1.0f - gW) * cWP;   // conv linear in wg
            wshW = pow_f(ws, gamW);
            float s = wshW;
            #pragma unroll
            for (int m = 1; m < 64; m <<= 1) s += __shfl_xor(s, m, 64);
            if (lane == 0) red[1][wv] = s;
        }
        __syncthreads();  // s7
        {
            const float4* rp = (const float4*)red[1];
            float Swsh = 0.0f;
            #pragma unroll
            for (int w4 = 0; w4 < 4; ++w4) { float4 p = rp[w4]; Swsh += p.x + p.y + p.z + p.w; }
            float wwn = wshW / (Swsh + EPSF);
            out[OFF_WW + t * NN + tid] = wwn;
            wwprev = wwn;
            // memory update + norm recompute; mh stays live, stored once
            const float4* e4p = (const float4*)sh_e;
            const float4* a4p = (const float4*)sh_a;
            float n0 = 0.0f, n1 = 0.0f, n2 = 0.0f, n3 = 0.0f;
            #pragma unroll
            for (int j4 = 0; j4 < 8; ++j4) {
                float4 e = e4p[j4], a = a4p[j4];
                float m0 = Mlo[4*j4]   * (1.0f - wwn * e.x) + wwn * a.x;
                float m1 = Mlo[4*j4+1] * (1.0f - wwn * e.y) + wwn * a.y;
                float m2 = Mlo[4*j4+2] * (1.0f - wwn * e.z) + wwn * a.z;
                float m3 = Mlo[4*j4+3] * (1.0f - wwn * e.w) + wwn * a.w;
                Mlo[4*j4] = m0; Mlo[4*j4+1] = m1; Mlo[4*j4+2] = m2; Mlo[4*j4+3] = m3;
                n0 += m0 * m0; n1 += m1 * m1; n2 += m2 * m2; n3 += m3 * m3;
            }
            #pragma unroll
            for (int k = 0; k < 8; ++k) {
                float4 e = e4p[8 + k], a = a4p[8 + k];
                float4 m = mh[k];
                m.x = m.x * (1.0f - wwn * e.x) + wwn * a.x;
                m.y = m.y * (1.0f - wwn * e.y) + wwn * a.y;
                m.z = m.z * (1.0f - wwn * e.z) + wwn * a.z;
                m.w = m.w * (1.0f - wwn * e.w) + wwn * a.w;
                mh[k] = m;
                ws_m[k * NN + tid] = m;
                n0 += m.x * m.x; n1 += m.y * m.y; n2 += m.z * m.z; n3 += m.w * m.w;
            }
            rown = sqrtf((n0 + n1) + (n2 + n3));
        }

        // ================= read addressing (on updated Mt; mh still live) =================
        float betaR = sh_scal[8], gR = sh_scal[9];
        float s0R = sh_scal[10], s1R = sh_scal[11], s2R = sh_scal[12];
        float gamR = sh_scal[13], knR = sh_scal[14];
        {
            const float4* k4 = (const float4*)sh_kr;
            float d0 = 0.0f, d1 = 0.0f, d2 = 0.0f, d3 = 0.0f;
            #pragma unroll
            for (int j4 = 0; j4 < 8; ++j4) {
                float4 k = k4[j4];
                d0 += Mlo[4*j4]   * k.x;
                d1 += Mlo[4*j4+1] * k.y;
                d2 += Mlo[4*j4+2] * k.z;
                d3 += Mlo[4*j4+3] * k.w;
            }
            #pragma unroll
            for (int k8 = 0; k8 < 8; ++k8) {
                float4 k = k4[8 + k8];
                d0 += mh[k8].x * k.x;
                d1 += mh[k8].y * k.y;
                d2 += mh[k8].z * k.z;
                d3 += mh[k8].w * k.w;
            }
            float dot = (d0 + d1) + (d2 + d3);
            float sim = dot / (rown * knR + EPSF);
            float ev = __expf(betaR * sim);
            sh_evbuf[tid] = ev;   // safe: all write-phase conv reads done before s7
            sh_wpbuf[tid] = rwprev;
            float s = ev;
            #pragma unroll
            for (int m = 1; m < 64; m <<= 1) s += __shfl_xor(s, m, 64);
            if (lane == 0) red[2][wv] = s;
        }
        __syncthreads();  // s8
        float wshR;
        {
            const float4* rp = (const float4*)red[2];
            float Sev = 0.0f;
            #pragma unroll
            for (int w4 = 0; w4 < 4; ++w4) { float4 p = rp[w4]; Sev += p.x + p.y + p.z + p.w; }
            int tm1 = (tid + NN - 1) & (NN - 1), tp1 = (tid + 1) & (NN - 1);
            float cEV = s0R * sh_evbuf[tm1] + s1R * sh_evbuf[tid] + s2R * sh_evbuf[tp1];
            float cWP = s0R * sh_wpbuf[tm1] + s1R * sh_wpbuf[tid] + s2R * sh_wpbuf[tp1];
            float ws = (gR / Sev) * cEV + (1.0f - gR) * cWP;
            wshR = pow_f(ws, gamR);
            float s = wshR;
            #pragma unroll
            for (int m = 1; m < 64; m <<= 1) s += __shfl_xor(s, m, 64);
            if (lane == 0) red[3][wv] = s;

            // r_n partials: per-wave column sums of wshR * Mrow via recursive-halving
            // transpose-reduce (verified v[16] pattern); chunks 0-1 from Mlo, 2-3 from mh.
            #pragma unroll
            for (int chunk = 0; chunk < 4; ++chunk) {
                const int cb = chunk * 16;
                float v[16];
                if (chunk < 2) {
                    #pragma unroll
                    for (int i = 0; i < 16; ++i) v[i] = wshR * Mlo[chunk * 16 + i];
                } else {
                    #pragma unroll
                    for (int k = 0; k < 4; ++k) {
                        float4 m = mh[(chunk - 2) * 4 + k];
                        v[4*k]   = wshR * m.x;
                        v[4*k+1] = wshR * m.y;
                        v[4*k+2] = wshR * m.z;
                        v[4*k+3] = wshR * m.w;
                    }
                }
                #pragma unroll
                for (int st = 0; st < 4; ++st) {
                    const int m = 1 << st;
                    const int hs = 8 >> st;
                    bool hi = (lane & m) != 0;
                    #pragma unroll
                    for (int i = 0; i < 8; ++i) {
                        if (i < hs) {
                            float send = hi ? v[i] : v[i + hs];
                            float recv = __shfl_xor(send, m, 64);
                            float keep = hi ? v[i + hs] : v[i];
                            v[i] = keep + recv;
                        }
                    }
                }
                float v0 = v[0];
                v0 += __shfl_xor(v0, 16, 64);
                v0 += __shfl_xor(v0, 32, 64);
                if (lane < 16) wmat[wv][cb + bitrev4(lane)] = v0;
            }
        }
        __syncthreads();  // s9
        {
            const float4* rp = (const float4*)red[3];
            float Swsh = 0.0f;
            #pragma unroll
            for (int w4 = 0; w4 < 4; ++w4) { float4 p = rp[w4]; Swsh += p.x + p.y + p.z + p.w; }
            float inv = 1.0f / (Swsh + EPSF);
            float rwn = wshR * inv;
            out[OFF_RW + t * NN + tid] = rwn;
            rwprev = rwn;
            if (tid < MM) {
                float rv = 0.0f;
                #pragma unroll
                for (int w = 0; w < 16; ++w) rv += wmat[w][tid];
                rv *= inv;
                sh_r[tid] = rv;
                out[OFF_R + t * MM + tid] = rv;
            }
        }
        __syncthreads();  // s10
        if (tid < LL) {
            const float4* r4p = (const float4*)sh_r;
            float a0 = 0.0f, a1 = 0.0f;
            #pragma unroll
            for (int i4 = 0; i4 < 16; ++i4) {
                float4 r = r4p[i4];
                a0 += r.x * sh_Wo[(4*i4) * LL + tid]   + r.y * sh_Wo[(4*i4+1) * LL + tid];
                a1 += r.z * sh_Wo[(4*i4+2) * LL + tid] + r.w * sh_Wo[(4*i4+3) * LL + tid];
            }
            float acc = sh_bo[tid] + a0 + a1;
            out[OFF_SEQ + t * LL + tid] = fminf(fmaxf(acc, 0.0f), 1.0f);
        }
        // no sync needed: next h-stage only reads sh_r (stable until next s9)
    }
}

extern "C" void kernel_launch(void* const* d_in, const int* in_sizes, int n_in,
                              void* d_out, int out_size, void* d_ws, size_t ws_size,
                              hipStream_t stream) {
    const float* seq = (const float*)d_in[0];
    const float* Wc  = (const float*)d_in[1];
    const float* bc  = (const float*)d_in[2];
    const float* Wr  = (const float*)d_in[3];
    const float* br  = (const float*)d_in[4];
    const float* Ww  = (const float*)d_in[5];
    const float* bw  = (const float*)d_in[6];
    const float* Wo  = (const float*)d_in[7];
    const float* bo  = (const float*)d_in[8];
    float* out = (float*)d_out;
    float* pre = (float*)d_ws;                         // 16 MB
    float4* ws_m = (float4*)((float*)d_ws + TT * CC);  // +128 KB private M cols 32..63

    pre_kernel<<<(TT * CC) / 256, 256, 0, stream>>>(seq, Wc, bc, pre);
    ntm_kernel<<<1, 1024, 0, stream>>>(pre, Wc, Wr, br, Ww, bw, Wo, bo, out, ws_m);
}